// Round 2
// baseline (694.214 us; speedup 1.0000x reference)
//
#include <hip/hip_runtime.h>

// ---------------- problem constants ----------------
#define NUM_GRAPHS 64
#define NODE_SZ    200
#define FEAT       200
#define HID        256
#define HALF       128
#define N_NODES    (NUM_GRAPHS * NODE_SZ)   // 12800
#define KREAD      (NODE_SZ * HID)          // 51200

// ---------------- CSR build ----------------
__global__ void hist_kernel(const int* __restrict__ ei, const float* __restrict__ ew,
                            int* __restrict__ counts, int* __restrict__ cnt_p,
                            int* __restrict__ cnt_n, int E) {
    int e = blockIdx.x * blockDim.x + threadIdx.x;
    if (e >= E) return;
    int dst = ei[E + e];
    float w = ew[e];
    atomicAdd(&counts[dst], 1);
    if (w > 0.0f)      atomicAdd(&cnt_p[dst], 1);
    else if (w < 0.0f) atomicAdd(&cnt_n[dst], 1);
}

__global__ void scan_kernel(const int* __restrict__ counts, int* __restrict__ offsets, int n) {
    __shared__ int buf[256];
    __shared__ int carry;
    if (threadIdx.x == 0) carry = 0;
    __syncthreads();
    for (int base = 0; base < n; base += 256) {
        int i = base + threadIdx.x;
        int v = (i < n) ? counts[i] : 0;
        buf[threadIdx.x] = v;
        __syncthreads();
        for (int d = 1; d < 256; d <<= 1) {
            int t = (threadIdx.x >= d) ? buf[threadIdx.x - d] : 0;
            __syncthreads();
            buf[threadIdx.x] += t;
            __syncthreads();
        }
        if (i < n) offsets[i] = carry + buf[threadIdx.x] - v;  // exclusive
        __syncthreads();
        if (threadIdx.x == 0) carry += buf[255];
        __syncthreads();
    }
    if (threadIdx.x == 0) offsets[n] = carry;
}

__global__ void scatter_kernel(const int* __restrict__ ei, const float* __restrict__ ew,
                               const int* __restrict__ offsets, int* __restrict__ cursor,
                               int* __restrict__ es_src, float* __restrict__ es_w, int E) {
    int e = blockIdx.x * blockDim.x + threadIdx.x;
    if (e >= E) return;
    int src = ei[e];
    int dst = ei[E + e];
    int pos = atomicAdd(&cursor[dst], 1);
    int at = offsets[dst] + pos;
    es_src[at] = src;
    es_w[at] = ew[e];
}

// ---------------- signed aggregation (one block per node) ----------------
// Writes Ap[n] = [agg_p/deg_p | h_n], An[n] = [agg_n/deg_n | h_n], rows of length K2=2D.
template <int D>
__global__ void agg_kernel(const float* __restrict__ h,
                           const int* __restrict__ offsets,
                           const int* __restrict__ cnt_p, const int* __restrict__ cnt_n,
                           const int* __restrict__ es_src, const float* __restrict__ es_w,
                           float* __restrict__ Ap, float* __restrict__ An) {
    constexpr int K2 = 2 * D;
    int n = blockIdx.x;
    int col = threadIdx.x;
    int off = offsets[n], end = offsets[n + 1];

    __shared__ int   s_src[256];
    __shared__ float s_w[256];

    float ap = 0.0f, an = 0.0f;
    for (int base = off; base < end; base += 256) {
        int cnt = min(256, end - base);
        if (threadIdx.x < cnt) {
            s_src[threadIdx.x] = es_src[base + threadIdx.x];
            s_w[threadIdx.x]   = es_w[base + threadIdx.x];
        }
        __syncthreads();
        if (col < D) {
            for (int i = 0; i < cnt; ++i) {
                int s = s_src[i];
                float w = s_w[i];
                float v = h[(size_t)s * D + col];
                ap = fmaf(fmaxf(w, 0.0f),  v, ap);
                an = fmaf(fmaxf(-w, 0.0f), v, an);
            }
        }
        __syncthreads();
    }
    if (col < D) {
        float dp = fmaxf((float)cnt_p[n], 1.0f);
        float dn = fmaxf((float)cnt_n[n], 1.0f);
        float self = h[(size_t)n * D + col];
        size_t base = (size_t)n * K2;
        Ap[base + col] = ap / dp;
        An[base + col] = an / dn;
        Ap[base + D + col] = self;
        An[base + D + col] = self;
    }
}

// ---------------- conv linear: hout[m, :] = leaky?(concat @ W.T + b) ----------------
// grid.x = M/64 tiles, grid.y = 4 column tiles (0,1 -> positive branch; 2,3 -> negative)
template <int K2, bool LEAKY>
__global__ __launch_bounds__(256) void conv_gemm(
        const float* __restrict__ Ap, const float* __restrict__ An,
        const float* __restrict__ Wp, const float* __restrict__ Wn,
        const float* __restrict__ bp, const float* __restrict__ bn,
        float* __restrict__ hout) {
    __shared__ float As[16][65];
    __shared__ float Bs[16][65];
    int mBase = blockIdx.x * 64;
    int nt = blockIdx.y;
    const float* A    = (nt < 2) ? Ap : An;
    const float* W    = (nt < 2) ? Wp : Wn;
    const float* bias = (nt < 2) ? bp : bn;
    int jBase = (nt & 1) * 64;   // within-branch output column base
    int tid = threadIdx.x;
    int tx = tid & 15, ty = tid >> 4;
    int lm = tid >> 2;           // 0..63  row loaded by this thread
    int lk = (tid & 3) * 4;      // 0,4,8,12

    float acc[4][4] = {};
    for (int k0 = 0; k0 < K2; k0 += 16) {
        float4 a4 = *(const float4*)&A[(size_t)(mBase + lm) * K2 + k0 + lk];
        float4 w4 = *(const float4*)&W[(size_t)(jBase + lm) * K2 + k0 + lk];
        As[lk + 0][lm] = a4.x; As[lk + 1][lm] = a4.y;
        As[lk + 2][lm] = a4.z; As[lk + 3][lm] = a4.w;
        Bs[lk + 0][lm] = w4.x; Bs[lk + 1][lm] = w4.y;
        Bs[lk + 2][lm] = w4.z; Bs[lk + 3][lm] = w4.w;
        __syncthreads();
#pragma unroll
        for (int k = 0; k < 16; ++k) {
            float a[4], b[4];
#pragma unroll
            for (int i = 0; i < 4; ++i) a[i] = As[k][ty + 16 * i];
#pragma unroll
            for (int j = 0; j < 4; ++j) b[j] = Bs[k][tx + 16 * j];
#pragma unroll
            for (int i = 0; i < 4; ++i)
#pragma unroll
                for (int j = 0; j < 4; ++j)
                    acc[i][j] = fmaf(a[i], b[j], acc[i][j]);
        }
        __syncthreads();
    }
    int colBase = (nt < 2) ? 0 : HALF;
#pragma unroll
    for (int i = 0; i < 4; ++i) {
        int m = mBase + ty + 16 * i;
#pragma unroll
        for (int j = 0; j < 4; ++j) {
            int jl = jBase + tx + 16 * j;       // 0..127 within branch
            float v = acc[i][j] + bias[jl];
            if (LEAKY) v = (v > 0.0f) ? v : 0.01f * v;
            hout[(size_t)m * HID + colBase + jl] = v;
        }
    }
}

// ---------------- readout GEMM: g_ws[64,256] += h[64,51200] @ Wr[256,51200].T ----------------
// grid.x = 4 column tiles of 64, grid.y = 64 K-chunks of 800
__global__ __launch_bounds__(256) void readout_gemm(
        const float* __restrict__ h, const float* __restrict__ Wr,
        float* __restrict__ g_ws) {
    __shared__ float As[16][65];
    __shared__ float Bs[16][65];
    int cBase = blockIdx.x * 64;
    int kStart = blockIdx.y * 800;
    int tid = threadIdx.x;
    int tx = tid & 15, ty = tid >> 4;
    int lm = tid >> 2;
    int lk = (tid & 3) * 4;

    float acc[4][4] = {};
    for (int k0 = 0; k0 < 800; k0 += 16) {
        float4 a4 = *(const float4*)&h[(size_t)lm * KREAD + kStart + k0 + lk];
        float4 w4 = *(const float4*)&Wr[(size_t)(cBase + lm) * KREAD + kStart + k0 + lk];
        As[lk + 0][lm] = a4.x; As[lk + 1][lm] = a4.y;
        As[lk + 2][lm] = a4.z; As[lk + 3][lm] = a4.w;
        Bs[lk + 0][lm] = w4.x; Bs[lk + 1][lm] = w4.y;
        Bs[lk + 2][lm] = w4.z; Bs[lk + 3][lm] = w4.w;
        __syncthreads();
#pragma unroll
        for (int k = 0; k < 16; ++k) {
            float a[4], b[4];
#pragma unroll
            for (int i = 0; i < 4; ++i) a[i] = As[k][ty + 16 * i];
#pragma unroll
            for (int j = 0; j < 4; ++j) b[j] = Bs[k][tx + 16 * j];
#pragma unroll
            for (int i = 0; i < 4; ++i)
#pragma unroll
                for (int j = 0; j < 4; ++j)
                    acc[i][j] = fmaf(a[i], b[j], acc[i][j]);
        }
        __syncthreads();
    }
#pragma unroll
    for (int i = 0; i < 4; ++i) {
        int g = ty + 16 * i;
#pragma unroll
        for (int j = 0; j < 4; ++j) {
            int c = cBase + tx + 16 * j;
            atomicAdd(&g_ws[g * HID + c], acc[i][j]);
        }
    }
}

// ---------------- final: out[g] = sum_c (g_ws+br)*Wl + bl ----------------
__global__ void final_kernel(const float* __restrict__ g_ws, const float* __restrict__ br,
                             const float* __restrict__ Wl, const float* __restrict__ bl,
                             float* __restrict__ out) {
    int g = blockIdx.x;
    int c = threadIdx.x;   // 256
    float v = (g_ws[g * HID + c] + br[c]) * Wl[c];
#pragma unroll
    for (int d = 32; d > 0; d >>= 1) v += __shfl_down(v, d);
    __shared__ float s[4];
    if ((c & 63) == 0) s[c >> 6] = v;
    __syncthreads();
    if (c == 0) out[g] = s[0] + s[1] + s[2] + s[3] + bl[0];
}

// ---------------- launch ----------------
extern "C" void kernel_launch(void* const* d_in, const int* in_sizes, int n_in,
                              void* d_out, int out_size, void* d_ws, size_t ws_size,
                              hipStream_t stream) {
    const float* x  = (const float*)d_in[0];
    const int*   ei = (const int*)d_in[1];
    const float* ew = (const float*)d_in[2];
    // d_in[3] = batch (unused; graphs are contiguous)
    const float* Wp0 = (const float*)d_in[4];
    const float* bp0 = (const float*)d_in[5];
    const float* Wn0 = (const float*)d_in[6];
    const float* bn0 = (const float*)d_in[7];
    const float* Wp1 = (const float*)d_in[8];
    const float* bp1 = (const float*)d_in[9];
    const float* Wn1 = (const float*)d_in[10];
    const float* bn1 = (const float*)d_in[11];
    const float* Wp2 = (const float*)d_in[12];
    const float* bp2 = (const float*)d_in[13];
    const float* Wn2 = (const float*)d_in[14];
    const float* bn2 = (const float*)d_in[15];
    const float* Wr  = (const float*)d_in[16];
    const float* br  = (const float*)d_in[17];
    const float* Wl  = (const float*)d_in[18];
    const float* bl  = (const float*)d_in[19];
    const int E = in_sizes[1] / 2;   // 409600

    // ---- workspace layout (bytes) ----
    char* ws = (char*)d_ws;
    int*   counts  = (int*)(ws + 0);            // 12800 ints
    int*   cursor  = (int*)(ws + 51200);
    int*   cnt_p   = (int*)(ws + 102400);
    int*   cnt_n   = (int*)(ws + 153600);
    float* g_ws    = (float*)(ws + 204800);     // 64*256 floats -> zero region ends 270336
    int*   offsets = (int*)(ws + 270336);       // 12801 ints (pad to 51264)
    int*   es_src  = (int*)(ws + 321600);       // E ints
    float* es_w    = (float*)(ws + 1960000);    // E floats
    float* Ap      = (float*)(ws + 3598400);    // 12800*512 fp32
    float* An      = (float*)(ws + 29812800);
    float* hA      = (float*)(ws + 56027200);   // 12800*256 fp32
    float* hB      = (float*)(ws + 69134400);   // end: 82241600

    hipMemsetAsync(d_ws, 0, 270336, stream);

    int eb = (E + 255) / 256;
    hipLaunchKernelGGL(hist_kernel, dim3(eb), dim3(256), 0, stream, ei, ew, counts, cnt_p, cnt_n, E);
    hipLaunchKernelGGL(scan_kernel, dim3(1), dim3(256), 0, stream, counts, offsets, N_NODES);
    hipLaunchKernelGGL(scatter_kernel, dim3(eb), dim3(256), 0, stream, ei, ew, offsets, cursor, es_src, es_w, E);

    // layer 0: in = x (D=200), K2=400
    hipLaunchKernelGGL((agg_kernel<FEAT>), dim3(N_NODES), dim3(256), 0, stream,
                       x, offsets, cnt_p, cnt_n, es_src, es_w, Ap, An);
    hipLaunchKernelGGL((conv_gemm<2 * FEAT, true>), dim3(N_NODES / 64, 4), dim3(256), 0, stream,
                       Ap, An, Wp0, Wn0, bp0, bn0, hA);
    // layer 1: in = hA (D=256), K2=512
    hipLaunchKernelGGL((agg_kernel<HID>), dim3(N_NODES), dim3(256), 0, stream,
                       hA, offsets, cnt_p, cnt_n, es_src, es_w, Ap, An);
    hipLaunchKernelGGL((conv_gemm<2 * HID, true>), dim3(N_NODES / 64, 4), dim3(256), 0, stream,
                       Ap, An, Wp1, Wn1, bp1, bn1, hB);
    // layer 2: in = hB, no activation
    hipLaunchKernelGGL((agg_kernel<HID>), dim3(N_NODES), dim3(256), 0, stream,
                       hB, offsets, cnt_p, cnt_n, es_src, es_w, Ap, An);
    hipLaunchKernelGGL((conv_gemm<2 * HID, false>), dim3(N_NODES / 64, 4), dim3(256), 0, stream,
                       Ap, An, Wp2, Wn2, bp2, bn2, hA);

    // readout + final
    hipLaunchKernelGGL(readout_gemm, dim3(4, 64), dim3(256), 0, stream, hA, Wr, g_ws);
    hipLaunchKernelGGL(final_kernel, dim3(NUM_GRAPHS), dim3(256), 0, stream,
                       g_ws, br, Wl, bl, (float*)d_out);
}

// Round 3
// 453.935 us; speedup vs baseline: 1.5293x; 1.5293x over previous
//
#include <hip/hip_runtime.h>

// ---------------- problem constants ----------------
#define NUM_GRAPHS 64
#define NODE_SZ    200
#define FEAT       200
#define HID        256
#define HALF       128
#define N_NODES    (NUM_GRAPHS * NODE_SZ)   // 12800
#define KREAD      (NODE_SZ * HID)          // 51200
#define KSTRIDE    512                      // padded K for conv inputs/weights

typedef unsigned short ushort_t;
typedef __attribute__((ext_vector_type(8))) short bf16x8;
typedef __attribute__((ext_vector_type(4))) float f32x4;

__device__ __forceinline__ float bf2f(ushort_t u) {
    union { unsigned int i; float f; } v; v.i = ((unsigned int)u) << 16; return v.f;
}
__device__ __forceinline__ ushort_t f2bf(float f) {
    union { float f; unsigned int i; } v; v.f = f;
    unsigned int x = v.i;
    unsigned int r = (x + 0x7fffu + ((x >> 16) & 1u)) >> 16;  // RNE
    return (ushort_t)r;
}

// ---------------- CSR build ----------------
__global__ void hist_kernel(const int* __restrict__ ei, const float* __restrict__ ew,
                            int* __restrict__ counts, int* __restrict__ cnt_p,
                            int* __restrict__ cnt_n, int E) {
    int e = blockIdx.x * blockDim.x + threadIdx.x;
    if (e >= E) return;
    int dst = ei[E + e];
    float w = ew[e];
    atomicAdd(&counts[dst], 1);
    if (w > 0.0f)      atomicAdd(&cnt_p[dst], 1);
    else if (w < 0.0f) atomicAdd(&cnt_n[dst], 1);
}

__global__ void scan_kernel(const int* __restrict__ counts, int* __restrict__ offsets, int n) {
    __shared__ int buf[256];
    __shared__ int carry;
    if (threadIdx.x == 0) carry = 0;
    __syncthreads();
    for (int base = 0; base < n; base += 256) {
        int i = base + threadIdx.x;
        int v = (i < n) ? counts[i] : 0;
        buf[threadIdx.x] = v;
        __syncthreads();
        for (int d = 1; d < 256; d <<= 1) {
            int t = (threadIdx.x >= d) ? buf[threadIdx.x - d] : 0;
            __syncthreads();
            buf[threadIdx.x] += t;
            __syncthreads();
        }
        if (i < n) offsets[i] = carry + buf[threadIdx.x] - v;  // exclusive
        __syncthreads();
        if (threadIdx.x == 0) carry += buf[255];
        __syncthreads();
    }
    if (threadIdx.x == 0) offsets[n] = carry;
}

__global__ void scatter_kernel(const int* __restrict__ ei, const float* __restrict__ ew,
                               const int* __restrict__ offsets, int* __restrict__ cursor,
                               int* __restrict__ es_src, float* __restrict__ es_w, int E) {
    int e = blockIdx.x * blockDim.x + threadIdx.x;
    if (e >= E) return;
    int src = ei[e];
    int dst = ei[E + e];
    int pos = atomicAdd(&cursor[dst], 1);
    int at = offsets[dst] + pos;
    es_src[at] = src;
    es_w[at] = ew[e];
}

// ---------------- weight casts ----------------
// conv weight: [rows x K2] fp32 -> [rows x KSTRIDE] bf16, zero-padded
__global__ void castpad_kernel(const float* __restrict__ W, ushort_t* __restrict__ Wb,
                               int K2, int total /* rows*KSTRIDE */) {
    int idx = blockIdx.x * 256 + threadIdx.x;
    if (idx >= total) return;
    int row = idx >> 9;
    int col = idx & (KSTRIDE - 1);
    Wb[idx] = (col < K2) ? f2bf(W[(size_t)row * K2 + col]) : (ushort_t)0;
}

// flat fp32 -> bf16 (n divisible by 4)
__global__ void cast_kernel(const float* __restrict__ W, ushort_t* __restrict__ Wb, int n) {
    int i = (blockIdx.x * 256 + threadIdx.x) * 4;
    if (i >= n) return;
    float4 v = *(const float4*)&W[i];
    ushort4 o;
    o.x = f2bf(v.x); o.y = f2bf(v.y); o.z = f2bf(v.z); o.w = f2bf(v.w);
    *(ushort4*)&Wb[i] = o;
}

// ---------------- signed aggregation (one block per node) ----------------
// Writes bf16 rows of stride KSTRIDE: Ap[n] = [agg_p/deg_p | h_n | pad0], An likewise.
template <int D, bool IN_BF16>
__global__ void agg_kernel(const void* __restrict__ hin,
                           const int* __restrict__ offsets,
                           const int* __restrict__ cnt_p, const int* __restrict__ cnt_n,
                           const int* __restrict__ es_src, const float* __restrict__ es_w,
                           ushort_t* __restrict__ Ap, ushort_t* __restrict__ An) {
    const float*    hf = (const float*)hin;
    const ushort_t* hb = (const ushort_t*)hin;
    int n = blockIdx.x;
    int col = threadIdx.x;
    int off = offsets[n], end = offsets[n + 1];

    __shared__ int   s_src[256];
    __shared__ float s_w[256];

    float ap = 0.0f, an = 0.0f;
    for (int base = off; base < end; base += 256) {
        int cnt = min(256, end - base);
        if (threadIdx.x < cnt) {
            s_src[threadIdx.x] = es_src[base + threadIdx.x];
            s_w[threadIdx.x]   = es_w[base + threadIdx.x];
        }
        __syncthreads();
        if (col < D) {
            for (int i = 0; i < cnt; ++i) {
                int s = s_src[i];
                float w = s_w[i];
                float v = IN_BF16 ? bf2f(hb[(size_t)s * D + col]) : hf[(size_t)s * D + col];
                ap = fmaf(fmaxf(w, 0.0f),  v, ap);
                an = fmaf(fmaxf(-w, 0.0f), v, an);
            }
        }
        __syncthreads();
    }
    size_t rb = (size_t)n * KSTRIDE;
    if (col < D) {
        float dp = fmaxf((float)cnt_p[n], 1.0f);
        float dn = fmaxf((float)cnt_n[n], 1.0f);
        float self = IN_BF16 ? bf2f(hb[(size_t)n * D + col]) : hf[(size_t)n * D + col];
        ushort_t sb = f2bf(self);
        Ap[rb + col] = f2bf(ap / dp);
        An[rb + col] = f2bf(an / dn);
        Ap[rb + D + col] = sb;
        An[rb + D + col] = sb;
    }
    if (D == 200 && col < 16) {   // zero the 400..415 pad that conv layer 0 reads
        Ap[rb + 400 + col] = 0;
        An[rb + 400 + col] = 0;
    }
}

// ---------------- conv linear via MFMA ----------------
// hout[m, branch*128 + n] = leaky?( sum_k A[m][k] * W[n][k] + bias[n] )
// grid.x = M/64, grid.y = 2 (branch: 0=pos, 1=neg). block = 256 (4 waves).
// Tile: 64 (M) x 128 (N, whole branch) x 32 (K-step). Wave w owns M-rows [w*16, w*16+16).
template <int KSTEPS, bool LEAKY>
__global__ __launch_bounds__(256) void conv_mfma(
        const ushort_t* __restrict__ Ap, const ushort_t* __restrict__ An,
        const ushort_t* __restrict__ Wpb, const ushort_t* __restrict__ Wnb,
        const float* __restrict__ bp, const float* __restrict__ bn,
        ushort_t* __restrict__ hout) {
    __shared__ __align__(16) ushort_t As[64 * 32];    // 4 KB
    __shared__ __align__(16) ushort_t Bs[128 * 32];   // 8 KB
    int mBase = blockIdx.x * 64;
    bool neg = (blockIdx.y != 0);
    const ushort_t* A    = neg ? An : Ap;
    const ushort_t* W    = neg ? Wnb : Wpb;
    const float*    bias = neg ? bn : bp;
    int tid  = threadIdx.x;
    int lane = tid & 63;
    int wv   = tid >> 6;
    int r    = lane & 15;
    int quad = lane >> 4;

    f32x4 acc[8];
#pragma unroll
    for (int j = 0; j < 8; ++j) acc[j] = (f32x4){0.f, 0.f, 0.f, 0.f};

    for (int kt = 0; kt < KSTEPS; ++kt) {
        int kBase = kt * 32;
        // stage A tile (64x32): 8 el / thread
        {
            int lin = tid * 8;
            int row = lin >> 5, col = lin & 31;
            *(uint4*)&As[lin] = *(const uint4*)&A[(size_t)(mBase + row) * KSTRIDE + kBase + col];
        }
        // stage B tile (128x32): 16 el / thread
        {
            int l0 = tid * 8;
            int row = l0 >> 5, col = l0 & 31;
            *(uint4*)&Bs[l0] = *(const uint4*)&W[(size_t)row * KSTRIDE + kBase + col];
            int l1 = l0 + 2048;
            row = l1 >> 5; col = l1 & 31;
            *(uint4*)&Bs[l1] = *(const uint4*)&W[(size_t)row * KSTRIDE + kBase + col];
        }
        __syncthreads();
        bf16x8 a = *(const bf16x8*)&As[(wv * 16 + r) * 32 + quad * 8];
#pragma unroll
        for (int j = 0; j < 8; ++j) {
            bf16x8 b = *(const bf16x8*)&Bs[(j * 16 + r) * 32 + quad * 8];
            acc[j] = __builtin_amdgcn_mfma_f32_16x16x32_bf16(a, b, acc[j], 0, 0, 0);
        }
        __syncthreads();
    }
    // epilogue: D[row = quad*4+reg][col = j*16+r]
    int colOff = neg ? HALF : 0;
#pragma unroll
    for (int j = 0; j < 8; ++j) {
        int c = j * 16 + r;
        float bv = bias[c];
#pragma unroll
        for (int reg = 0; reg < 4; ++reg) {
            int m = mBase + wv * 16 + quad * 4 + reg;
            float v = acc[j][reg] + bv;
            if (LEAKY) v = (v > 0.0f) ? v : 0.01f * v;
            hout[(size_t)m * HID + colOff + c] = f2bf(v);
        }
    }
}

// ---------------- readout via MFMA, split-K ----------------
// g_ws[64,256] += h[64,51200] @ Wr[256,51200].T   (both bf16, K-contiguous)
// grid.x = 4 (N tiles of 64), grid.y = 64 (K chunks of 800 = 25*32). block = 256.
__global__ __launch_bounds__(256) void readout_mfma(
        const ushort_t* __restrict__ h, const ushort_t* __restrict__ Wrb,
        float* __restrict__ g_ws) {
    __shared__ __align__(16) ushort_t As[64 * 32];
    __shared__ __align__(16) ushort_t Bs[64 * 32];
    int nBase  = blockIdx.x * 64;
    int kStart = blockIdx.y * 800;
    int tid  = threadIdx.x;
    int lane = tid & 63;
    int wv   = tid >> 6;
    int r    = lane & 15;
    int quad = lane >> 4;

    f32x4 acc[4];
#pragma unroll
    for (int j = 0; j < 4; ++j) acc[j] = (f32x4){0.f, 0.f, 0.f, 0.f};

    for (int kt = 0; kt < 25; ++kt) {
        int kBase = kStart + kt * 32;
        int lin = tid * 8;
        int row = lin >> 5, col = lin & 31;
        *(uint4*)&As[lin] = *(const uint4*)&h[(size_t)row * KREAD + kBase + col];
        *(uint4*)&Bs[lin] = *(const uint4*)&Wrb[(size_t)(nBase + row) * KREAD + kBase + col];
        __syncthreads();
        bf16x8 a = *(const bf16x8*)&As[(wv * 16 + r) * 32 + quad * 8];
#pragma unroll
        for (int j = 0; j < 4; ++j) {
            bf16x8 b = *(const bf16x8*)&Bs[(j * 16 + r) * 32 + quad * 8];
            acc[j] = __builtin_amdgcn_mfma_f32_16x16x32_bf16(a, b, acc[j], 0, 0, 0);
        }
        __syncthreads();
    }
#pragma unroll
    for (int j = 0; j < 4; ++j) {
        int c = nBase + j * 16 + r;
#pragma unroll
        for (int reg = 0; reg < 4; ++reg) {
            int g = wv * 16 + quad * 4 + reg;
            atomicAdd(&g_ws[g * HID + c], acc[j][reg]);
        }
    }
}

// ---------------- final: out[g] = sum_c (g_ws+br)*Wl + bl ----------------
__global__ void final_kernel(const float* __restrict__ g_ws, const float* __restrict__ br,
                             const float* __restrict__ Wl, const float* __restrict__ bl,
                             float* __restrict__ out) {
    int g = blockIdx.x;
    int c = threadIdx.x;   // 256
    float v = (g_ws[g * HID + c] + br[c]) * Wl[c];
#pragma unroll
    for (int d = 32; d > 0; d >>= 1) v += __shfl_down(v, d);
    __shared__ float s[4];
    if ((c & 63) == 0) s[c >> 6] = v;
    __syncthreads();
    if (c == 0) out[g] = s[0] + s[1] + s[2] + s[3] + bl[0];
}

// ---------------- launch ----------------
extern "C" void kernel_launch(void* const* d_in, const int* in_sizes, int n_in,
                              void* d_out, int out_size, void* d_ws, size_t ws_size,
                              hipStream_t stream) {
    const float* x  = (const float*)d_in[0];
    const int*   ei = (const int*)d_in[1];
    const float* ew = (const float*)d_in[2];
    // d_in[3] = batch (unused; graphs are contiguous)
    const float* Wp0 = (const float*)d_in[4];
    const float* bp0 = (const float*)d_in[5];
    const float* Wn0 = (const float*)d_in[6];
    const float* bn0 = (const float*)d_in[7];
    const float* Wp1 = (const float*)d_in[8];
    const float* bp1 = (const float*)d_in[9];
    const float* Wn1 = (const float*)d_in[10];
    const float* bn1 = (const float*)d_in[11];
    const float* Wp2 = (const float*)d_in[12];
    const float* bp2 = (const float*)d_in[13];
    const float* Wn2 = (const float*)d_in[14];
    const float* bn2 = (const float*)d_in[15];
    const float* Wr  = (const float*)d_in[16];
    const float* br  = (const float*)d_in[17];
    const float* Wl  = (const float*)d_in[18];
    const float* bl  = (const float*)d_in[19];
    const int E = in_sizes[1] / 2;   // 409600

    // ---- workspace layout (bytes) ----
    char* ws = (char*)d_ws;
    int*      counts  = (int*)(ws + 0);            // 12800 ints
    int*      cursor  = (int*)(ws + 51200);
    int*      cnt_p   = (int*)(ws + 102400);
    int*      cnt_n   = (int*)(ws + 153600);
    float*    g_ws    = (float*)(ws + 204800);     // 64*256 fp32; zero region ends 270336
    int*      offsets = (int*)(ws + 270336);       // 12801 ints (reserve 51264)
    int*      es_src  = (int*)(ws + 321600);       // E ints
    float*    es_w    = (float*)(ws + 1960000);    // E floats
    ushort_t* Ap      = (ushort_t*)(ws + 3598400);   // 12800*512 bf16 = 13107200 B
    ushort_t* An      = (ushort_t*)(ws + 16705600);
    ushort_t* hA      = (ushort_t*)(ws + 29812800);  // 12800*256 bf16 = 6553600 B
    ushort_t* hB      = (ushort_t*)(ws + 36366400);
    ushort_t* wcast   = (ushort_t*)(ws + 42920000);  // 6 x 128*512 bf16 = 131072 B each
    ushort_t* Wrb     = (ushort_t*)(ws + 43706432);  // 256*51200 bf16 = 26214400 B -> ends 69920832

    ushort_t* w0p = wcast + 0 * 65536;
    ushort_t* w0n = wcast + 1 * 65536;
    ushort_t* w1p = wcast + 2 * 65536;
    ushort_t* w1n = wcast + 3 * 65536;
    ushort_t* w2p = wcast + 4 * 65536;
    ushort_t* w2n = wcast + 5 * 65536;

    hipMemsetAsync(d_ws, 0, 270336, stream);

    int eb = (E + 255) / 256;
    hipLaunchKernelGGL(hist_kernel, dim3(eb), dim3(256), 0, stream, ei, ew, counts, cnt_p, cnt_n, E);
    hipLaunchKernelGGL(scan_kernel, dim3(1), dim3(256), 0, stream, counts, offsets, N_NODES);
    hipLaunchKernelGGL(scatter_kernel, dim3(eb), dim3(256), 0, stream, ei, ew, offsets, cursor, es_src, es_w, E);

    // weight casts (independent of CSR)
    const int wtot = HALF * KSTRIDE;                 // 65536
    hipLaunchKernelGGL(castpad_kernel, dim3(wtot / 256), dim3(256), 0, stream, Wp0, w0p, 400, wtot);
    hipLaunchKernelGGL(castpad_kernel, dim3(wtot / 256), dim3(256), 0, stream, Wn0, w0n, 400, wtot);
    hipLaunchKernelGGL(castpad_kernel, dim3(wtot / 256), dim3(256), 0, stream, Wp1, w1p, 512, wtot);
    hipLaunchKernelGGL(castpad_kernel, dim3(wtot / 256), dim3(256), 0, stream, Wn1, w1n, 512, wtot);
    hipLaunchKernelGGL(castpad_kernel, dim3(wtot / 256), dim3(256), 0, stream, Wp2, w2p, 512, wtot);
    hipLaunchKernelGGL(castpad_kernel, dim3(wtot / 256), dim3(256), 0, stream, Wn2, w2n, 512, wtot);
    hipLaunchKernelGGL(cast_kernel, dim3((HID * KREAD / 4 + 255) / 256), dim3(256), 0, stream,
                       Wr, Wrb, HID * KREAD);

    // layer 0: in = x (fp32, D=200), KSTEPS = 13 (covers padded 416)
    hipLaunchKernelGGL((agg_kernel<FEAT, false>), dim3(N_NODES), dim3(256), 0, stream,
                       (const void*)x, offsets, cnt_p, cnt_n, es_src, es_w, Ap, An);
    hipLaunchKernelGGL((conv_mfma<13, true>), dim3(N_NODES / 64, 2), dim3(256), 0, stream,
                       Ap, An, w0p, w0n, bp0, bn0, hA);
    // layer 1: in = hA (bf16, D=256), KSTEPS = 16
    hipLaunchKernelGGL((agg_kernel<HID, true>), dim3(N_NODES), dim3(256), 0, stream,
                       (const void*)hA, offsets, cnt_p, cnt_n, es_src, es_w, Ap, An);
    hipLaunchKernelGGL((conv_mfma<16, true>), dim3(N_NODES / 64, 2), dim3(256), 0, stream,
                       Ap, An, w1p, w1n, bp1, bn1, hB);
    // layer 2: in = hB, no activation
    hipLaunchKernelGGL((agg_kernel<HID, true>), dim3(N_NODES), dim3(256), 0, stream,
                       (const void*)hB, offsets, cnt_p, cnt_n, es_src, es_w, Ap, An);
    hipLaunchKernelGGL((conv_mfma<16, false>), dim3(N_NODES / 64, 2), dim3(256), 0, stream,
                       Ap, An, w2p, w2n, bp2, bn2, hA);

    // readout + final
    hipLaunchKernelGGL(readout_mfma, dim3(4, 64), dim3(256), 0, stream, hA, Wrb, g_ws);
    hipLaunchKernelGGL(final_kernel, dim3(NUM_GRAPHS), dim3(256), 0, stream,
                       g_ws, br, Wl, bl, (float*)d_out);
}

// Round 4
// 378.695 us; speedup vs baseline: 1.8332x; 1.1987x over previous
//
#include <hip/hip_runtime.h>

// ---------------- problem constants ----------------
#define NUM_GRAPHS 64
#define NODE_SZ    200
#define FEAT       200
#define HID        256
#define HALF       128
#define N_NODES    (NUM_GRAPHS * NODE_SZ)   // 12800
#define KREAD      (NODE_SZ * HID)          // 51200
#define KSTRIDE    512                      // padded K for conv inputs/weights

typedef unsigned short ushort_t;
typedef __attribute__((ext_vector_type(8))) short bf16x8;
typedef __attribute__((ext_vector_type(4))) float f32x4;

__device__ __forceinline__ float bf2f(ushort_t u) {
    union { unsigned int i; float f; } v; v.i = ((unsigned int)u) << 16; return v.f;
}
__device__ __forceinline__ ushort_t f2bf(float f) {
    union { float f; unsigned int i; } v; v.f = f;
    unsigned int x = v.i;
    unsigned int r = (x + 0x7fffu + ((x >> 16) & 1u)) >> 16;  // RNE
    return (ushort_t)r;
}

// ---------------- CSR build ----------------
__global__ void hist_kernel(const int* __restrict__ ei, const float* __restrict__ ew,
                            int* __restrict__ counts, int* __restrict__ cnt_p,
                            int* __restrict__ cnt_n, int E) {
    int e = blockIdx.x * blockDim.x + threadIdx.x;
    if (e >= E) return;
    int dst = ei[E + e];
    float w = ew[e];
    atomicAdd(&counts[dst], 1);
    if (w > 0.0f)      atomicAdd(&cnt_p[dst], 1);
    else if (w < 0.0f) atomicAdd(&cnt_n[dst], 1);
}

// single block, 1024 threads, 13 elements/thread; register prefix + shfl wave scan
__global__ __launch_bounds__(1024) void scan_kernel(const int* __restrict__ counts,
                                                    int* __restrict__ offsets, int n) {
    const int PER = 13;                       // 1024*13 = 13312 >= 12800
    int t = threadIdx.x;
    int start = t * PER;
    int local[PER];
    int sum = 0;
#pragma unroll
    for (int i = 0; i < PER; ++i) {
        int idx = start + i;
        int v = (idx < n) ? counts[idx] : 0;
        local[i] = sum;                       // exclusive within thread
        sum += v;
    }
    int lane = t & 63, wid = t >> 6;          // 16 waves
    int inc = sum;
#pragma unroll
    for (int d = 1; d < 64; d <<= 1) {
        int up = __shfl_up(inc, d);
        if (lane >= d) inc += up;
    }
    __shared__ int wsum[16], woff[16];
    if (lane == 63) wsum[wid] = inc;
    __syncthreads();
    if (t < 16) {
        int acc = 0;
        for (int j = 0; j < 16; ++j) if (j < t) acc += wsum[j];
        woff[t] = acc;
    }
    __syncthreads();
    int base = woff[wid] + (inc - sum);       // exclusive prefix of this thread
#pragma unroll
    for (int i = 0; i < PER; ++i) {
        int idx = start + i;
        if (idx < n) offsets[idx] = base + local[i];
    }
    if (t == 1023) offsets[n] = base + sum;   // grand total
}

__global__ void scatter_kernel(const int* __restrict__ ei, const float* __restrict__ ew,
                               const int* __restrict__ offsets, int* __restrict__ cursor,
                               int* __restrict__ es_src, float* __restrict__ es_w, int E) {
    int e = blockIdx.x * blockDim.x + threadIdx.x;
    if (e >= E) return;
    int src = ei[e];
    int dst = ei[E + e];
    int pos = atomicAdd(&cursor[dst], 1);
    int at = offsets[dst] + pos;
    es_src[at] = src;
    es_w[at] = ew[e];
}

// ---------------- weight casts ----------------
__global__ void castpad_kernel(const float* __restrict__ W, ushort_t* __restrict__ Wb,
                               int K2, int total /* rows*KSTRIDE */) {
    int idx = blockIdx.x * 256 + threadIdx.x;
    if (idx >= total) return;
    int row = idx >> 9;
    int col = idx & (KSTRIDE - 1);
    Wb[idx] = (col < K2) ? f2bf(W[(size_t)row * K2 + col]) : (ushort_t)0;
}

__global__ void cast_kernel(const float* __restrict__ W, ushort_t* __restrict__ Wb, int n) {
    int i = (blockIdx.x * 256 + threadIdx.x) * 4;
    if (i >= n) return;
    float4 v = *(const float4*)&W[i];
    ushort4 o;
    o.x = f2bf(v.x); o.y = f2bf(v.y); o.z = f2bf(v.z); o.w = f2bf(v.w);
    *(ushort4*)&Wb[i] = o;
}

// ---------------- signed aggregation: one wave per node, 4 cols per lane ----------------
// Writes bf16 rows of stride KSTRIDE: [agg | self | pad0]. Edge order = CSR order (serial).
template <int D, bool IN_BF16>
__global__ __launch_bounds__(64) void agg_kernel(const void* __restrict__ hin,
                           const int* __restrict__ offsets,
                           const int* __restrict__ cnt_p, const int* __restrict__ cnt_n,
                           const int* __restrict__ es_src, const float* __restrict__ es_w,
                           ushort_t* __restrict__ Ap, ushort_t* __restrict__ An) {
    constexpr int ACT = D / 4;                // active lanes: 50 (fp32 D=200) or 64 (bf16 D=256)
    const float*    hf = (const float*)hin;
    const ushort_t* hb = (const ushort_t*)hin;
    int n = blockIdx.x;
    int lane = threadIdx.x;
    int c0 = lane * 4;
    int off = offsets[n], end = offsets[n + 1];

    __shared__ int   s_src[64];
    __shared__ float s_w[64];

    float ap[4] = {0.f, 0.f, 0.f, 0.f};
    float an[4] = {0.f, 0.f, 0.f, 0.f};
    for (int base = off; base < end; base += 64) {
        int cnt = min(64, end - base);
        if (lane < cnt) {
            s_src[lane] = es_src[base + lane];
            s_w[lane]   = es_w[base + lane];
        }
        __syncthreads();
        if (lane < ACT) {
            for (int i = 0; i < cnt; ++i) {
                int s = s_src[i];
                float w = s_w[i];
                float wp = fmaxf(w, 0.0f), wn = fmaxf(-w, 0.0f);
                float v[4];
                if (IN_BF16) {
                    uint2 pk = *(const uint2*)&hb[(size_t)s * D + c0];
                    const ushort_t* p = (const ushort_t*)&pk;
#pragma unroll
                    for (int c = 0; c < 4; ++c) v[c] = bf2f(p[c]);
                } else {
                    float4 pk = *(const float4*)&hf[(size_t)s * D + c0];
                    v[0] = pk.x; v[1] = pk.y; v[2] = pk.z; v[3] = pk.w;
                }
#pragma unroll
                for (int c = 0; c < 4; ++c) {
                    ap[c] = fmaf(wp, v[c], ap[c]);
                    an[c] = fmaf(wn, v[c], an[c]);
                }
            }
        }
        __syncthreads();
    }
    size_t rb = (size_t)n * KSTRIDE;
    if (lane < ACT) {
        float dp = fmaxf((float)cnt_p[n], 1.0f);
        float dn = fmaxf((float)cnt_n[n], 1.0f);
        ushort4 op, on, os;
        float sv[4];
        if (IN_BF16) {
            uint2 pk = *(const uint2*)&hb[(size_t)n * D + c0];
            const ushort_t* p = (const ushort_t*)&pk;
            os.x = p[0]; os.y = p[1]; os.z = p[2]; os.w = p[3];
        } else {
            float4 pk = *(const float4*)&hf[(size_t)n * D + c0];
            sv[0] = pk.x; sv[1] = pk.y; sv[2] = pk.z; sv[3] = pk.w;
            os.x = f2bf(sv[0]); os.y = f2bf(sv[1]); os.z = f2bf(sv[2]); os.w = f2bf(sv[3]);
        }
        op.x = f2bf(ap[0] / dp); op.y = f2bf(ap[1] / dp);
        op.z = f2bf(ap[2] / dp); op.w = f2bf(ap[3] / dp);
        on.x = f2bf(an[0] / dn); on.y = f2bf(an[1] / dn);
        on.z = f2bf(an[2] / dn); on.w = f2bf(an[3] / dn);
        *(ushort4*)&Ap[rb + c0] = op;
        *(ushort4*)&An[rb + c0] = on;
        *(ushort4*)&Ap[rb + D + c0] = os;
        *(ushort4*)&An[rb + D + c0] = os;
    }
    if (D == 200 && lane >= 50 && lane < 54) {   // zero pad cols 400..415
        ushort4 z = {0, 0, 0, 0};
        *(ushort4*)&Ap[rb + 400 + (lane - 50) * 4] = z;
        *(ushort4*)&An[rb + 400 + (lane - 50) * 4] = z;
    }
}

// ---------------- conv linear via MFMA ----------------
// grid.x = M/64, grid.y = 2 (branch). block = 256 (4 waves). Tile 64x128x32.
template <int KSTEPS, bool LEAKY>
__global__ __launch_bounds__(256) void conv_mfma(
        const ushort_t* __restrict__ Ap, const ushort_t* __restrict__ An,
        const ushort_t* __restrict__ Wpb, const ushort_t* __restrict__ Wnb,
        const float* __restrict__ bp, const float* __restrict__ bn,
        ushort_t* __restrict__ hout) {
    __shared__ __align__(16) ushort_t As[64 * 32];    // 4 KB
    __shared__ __align__(16) ushort_t Bs[128 * 32];   // 8 KB
    int mBase = blockIdx.x * 64;
    bool neg = (blockIdx.y != 0);
    const ushort_t* A    = neg ? An : Ap;
    const ushort_t* W    = neg ? Wnb : Wpb;
    const float*    bias = neg ? bn : bp;
    int tid  = threadIdx.x;
    int lane = tid & 63;
    int wv   = tid >> 6;
    int r    = lane & 15;
    int quad = lane >> 4;

    f32x4 acc[8];
#pragma unroll
    for (int j = 0; j < 8; ++j) acc[j] = (f32x4){0.f, 0.f, 0.f, 0.f};

    for (int kt = 0; kt < KSTEPS; ++kt) {
        int kBase = kt * 32;
        {
            int lin = tid * 8;
            int row = lin >> 5, col = lin & 31;
            *(uint4*)&As[lin] = *(const uint4*)&A[(size_t)(mBase + row) * KSTRIDE + kBase + col];
        }
        {
            int l0 = tid * 8;
            int row = l0 >> 5, col = l0 & 31;
            *(uint4*)&Bs[l0] = *(const uint4*)&W[(size_t)row * KSTRIDE + kBase + col];
            int l1 = l0 + 2048;
            row = l1 >> 5; col = l1 & 31;
            *(uint4*)&Bs[l1] = *(const uint4*)&W[(size_t)row * KSTRIDE + kBase + col];
        }
        __syncthreads();
        bf16x8 a = *(const bf16x8*)&As[(wv * 16 + r) * 32 + quad * 8];
#pragma unroll
        for (int j = 0; j < 8; ++j) {
            bf16x8 b = *(const bf16x8*)&Bs[(j * 16 + r) * 32 + quad * 8];
            acc[j] = __builtin_amdgcn_mfma_f32_16x16x32_bf16(a, b, acc[j], 0, 0, 0);
        }
        __syncthreads();
    }
    int colOff = neg ? HALF : 0;
#pragma unroll
    for (int j = 0; j < 8; ++j) {
        int c = j * 16 + r;
        float bv = bias[c];
#pragma unroll
        for (int reg = 0; reg < 4; ++reg) {
            int m = mBase + wv * 16 + quad * 4 + reg;
            float v = acc[j][reg] + bv;
            if (LEAKY) v = (v > 0.0f) ? v : 0.01f * v;
            hout[(size_t)m * HID + colOff + c] = f2bf(v);
        }
    }
}

// ---------------- readout via MFMA, split-K ----------------
// grid.x = 4 (N tiles of 64), grid.y = 64 (K chunks of 800). block = 256.
__global__ __launch_bounds__(256) void readout_mfma(
        const ushort_t* __restrict__ h, const ushort_t* __restrict__ Wrb,
        float* __restrict__ g_ws) {
    __shared__ __align__(16) ushort_t As[64 * 32];
    __shared__ __align__(16) ushort_t Bs[64 * 32];
    int nBase  = blockIdx.x * 64;
    int kStart = blockIdx.y * 800;
    int tid  = threadIdx.x;
    int lane = tid & 63;
    int wv   = tid >> 6;
    int r    = lane & 15;
    int quad = lane >> 4;

    f32x4 acc[4];
#pragma unroll
    for (int j = 0; j < 4; ++j) acc[j] = (f32x4){0.f, 0.f, 0.f, 0.f};

    for (int kt = 0; kt < 25; ++kt) {
        int kBase = kStart + kt * 32;
        int lin = tid * 8;
        int row = lin >> 5, col = lin & 31;
        *(uint4*)&As[lin] = *(const uint4*)&h[(size_t)row * KREAD + kBase + col];
        *(uint4*)&Bs[lin] = *(const uint4*)&Wrb[(size_t)(nBase + row) * KREAD + kBase + col];
        __syncthreads();
        bf16x8 a = *(const bf16x8*)&As[(wv * 16 + r) * 32 + quad * 8];
#pragma unroll
        for (int j = 0; j < 4; ++j) {
            bf16x8 b = *(const bf16x8*)&Bs[(j * 16 + r) * 32 + quad * 8];
            acc[j] = __builtin_amdgcn_mfma_f32_16x16x32_bf16(a, b, acc[j], 0, 0, 0);
        }
        __syncthreads();
    }
#pragma unroll
    for (int j = 0; j < 4; ++j) {
        int c = nBase + j * 16 + r;
#pragma unroll
        for (int reg = 0; reg < 4; ++reg) {
            int g = wv * 16 + quad * 4 + reg;
            atomicAdd(&g_ws[g * HID + c], acc[j][reg]);
        }
    }
}

// ---------------- final: out[g] = sum_c (g_ws+br)*Wl + bl ----------------
__global__ void final_kernel(const float* __restrict__ g_ws, const float* __restrict__ br,
                             const float* __restrict__ Wl, const float* __restrict__ bl,
                             float* __restrict__ out) {
    int g = blockIdx.x;
    int c = threadIdx.x;   // 256
    float v = (g_ws[g * HID + c] + br[c]) * Wl[c];
#pragma unroll
    for (int d = 32; d > 0; d >>= 1) v += __shfl_down(v, d);
    __shared__ float s[4];
    if ((c & 63) == 0) s[c >> 6] = v;
    __syncthreads();
    if (c == 0) out[g] = s[0] + s[1] + s[2] + s[3] + bl[0];
}

// ---------------- launch ----------------
extern "C" void kernel_launch(void* const* d_in, const int* in_sizes, int n_in,
                              void* d_out, int out_size, void* d_ws, size_t ws_size,
                              hipStream_t stream) {
    const float* x  = (const float*)d_in[0];
    const int*   ei = (const int*)d_in[1];
    const float* ew = (const float*)d_in[2];
    // d_in[3] = batch (unused; graphs are contiguous)
    const float* Wp0 = (const float*)d_in[4];
    const float* bp0 = (const float*)d_in[5];
    const float* Wn0 = (const float*)d_in[6];
    const float* bn0 = (const float*)d_in[7];
    const float* Wp1 = (const float*)d_in[8];
    const float* bp1 = (const float*)d_in[9];
    const float* Wn1 = (const float*)d_in[10];
    const float* bn1 = (const float*)d_in[11];
    const float* Wp2 = (const float*)d_in[12];
    const float* bp2 = (const float*)d_in[13];
    const float* Wn2 = (const float*)d_in[14];
    const float* bn2 = (const float*)d_in[15];
    const float* Wr  = (const float*)d_in[16];
    const float* br  = (const float*)d_in[17];
    const float* Wl  = (const float*)d_in[18];
    const float* bl  = (const float*)d_in[19];
    const int E = in_sizes[1] / 2;   // 409600

    // ---- workspace layout (bytes) ----
    char* ws = (char*)d_ws;
    int*      counts  = (int*)(ws + 0);            // 12800 ints
    int*      cursor  = (int*)(ws + 51200);
    int*      cnt_p   = (int*)(ws + 102400);
    int*      cnt_n   = (int*)(ws + 153600);
    float*    g_ws    = (float*)(ws + 204800);     // 64*256 fp32; zero region ends 270336
    int*      offsets = (int*)(ws + 270336);       // 12801 ints (reserve 51264)
    int*      es_src  = (int*)(ws + 321600);       // E ints
    float*    es_w    = (float*)(ws + 1960000);    // E floats
    ushort_t* Ap      = (ushort_t*)(ws + 3598400);   // 12800*512 bf16
    ushort_t* An      = (ushort_t*)(ws + 16705600);
    ushort_t* hA      = (ushort_t*)(ws + 29812800);  // 12800*256 bf16
    ushort_t* hB      = (ushort_t*)(ws + 36366400);
    ushort_t* wcast   = (ushort_t*)(ws + 42920000);  // 6 x 128*512 bf16
    ushort_t* Wrb     = (ushort_t*)(ws + 43706432);  // 256*51200 bf16 -> ends 69920832

    ushort_t* w0p = wcast + 0 * 65536;
    ushort_t* w0n = wcast + 1 * 65536;
    ushort_t* w1p = wcast + 2 * 65536;
    ushort_t* w1n = wcast + 3 * 65536;
    ushort_t* w2p = wcast + 4 * 65536;
    ushort_t* w2n = wcast + 5 * 65536;

    hipMemsetAsync(d_ws, 0, 270336, stream);

    int eb = (E + 255) / 256;
    hipLaunchKernelGGL(hist_kernel, dim3(eb), dim3(256), 0, stream, ei, ew, counts, cnt_p, cnt_n, E);
    hipLaunchKernelGGL(scan_kernel, dim3(1), dim3(1024), 0, stream, counts, offsets, N_NODES);
    hipLaunchKernelGGL(scatter_kernel, dim3(eb), dim3(256), 0, stream, ei, ew, offsets, cursor, es_src, es_w, E);

    // weight casts (independent of CSR)
    const int wtot = HALF * KSTRIDE;                 // 65536
    hipLaunchKernelGGL(castpad_kernel, dim3(wtot / 256), dim3(256), 0, stream, Wp0, w0p, 400, wtot);
    hipLaunchKernelGGL(castpad_kernel, dim3(wtot / 256), dim3(256), 0, stream, Wn0, w0n, 400, wtot);
    hipLaunchKernelGGL(castpad_kernel, dim3(wtot / 256), dim3(256), 0, stream, Wp1, w1p, 512, wtot);
    hipLaunchKernelGGL(castpad_kernel, dim3(wtot / 256), dim3(256), 0, stream, Wn1, w1n, 512, wtot);
    hipLaunchKernelGGL(castpad_kernel, dim3(wtot / 256), dim3(256), 0, stream, Wp2, w2p, 512, wtot);
    hipLaunchKernelGGL(castpad_kernel, dim3(wtot / 256), dim3(256), 0, stream, Wn2, w2n, 512, wtot);
    hipLaunchKernelGGL(cast_kernel, dim3((HID * KREAD / 4 + 255) / 256), dim3(256), 0, stream,
                       Wr, Wrb, HID * KREAD);

    // layer 0: in = x (fp32, D=200), KSTEPS = 13 (covers padded 416)
    hipLaunchKernelGGL((agg_kernel<FEAT, false>), dim3(N_NODES), dim3(64), 0, stream,
                       (const void*)x, offsets, cnt_p, cnt_n, es_src, es_w, Ap, An);
    hipLaunchKernelGGL((conv_mfma<13, true>), dim3(N_NODES / 64, 2), dim3(256), 0, stream,
                       Ap, An, w0p, w0n, bp0, bn0, hA);
    // layer 1: in = hA (bf16, D=256), KSTEPS = 16
    hipLaunchKernelGGL((agg_kernel<HID, true>), dim3(N_NODES), dim3(64), 0, stream,
                       (const void*)hA, offsets, cnt_p, cnt_n, es_src, es_w, Ap, An);
    hipLaunchKernelGGL((conv_mfma<16, true>), dim3(N_NODES / 64, 2), dim3(256), 0, stream,
                       Ap, An, w1p, w1n, bp1, bn1, hB);
    // layer 2: in = hB, no activation
    hipLaunchKernelGGL((agg_kernel<HID, true>), dim3(N_NODES), dim3(64), 0, stream,
                       (const void*)hB, offsets, cnt_p, cnt_n, es_src, es_w, Ap, An);
    hipLaunchKernelGGL((conv_mfma<16, false>), dim3(N_NODES / 64, 2), dim3(256), 0, stream,
                       Ap, An, w2p, w2n, bp2, bn2, hA);

    // readout + final
    hipLaunchKernelGGL(readout_mfma, dim3(4, 64), dim3(256), 0, stream, hA, Wrb, g_ws);
    hipLaunchKernelGGL(final_kernel, dim3(NUM_GRAPHS), dim3(256), 0, stream,
                       g_ws, br, Wl, bl, (float*)d_out);
}